// Round 1
// baseline (1939.038 us; speedup 1.0000x reference)
//
#include <hip/hip_runtime.h>
#include <math.h>

// SimpPointNet fused pipeline, fp32 baseline (round 1).
// Layout: all activations stored channel-major [C][M], M = B*N = 65536, m = b*2048 + n.
// BN(batch stats) applied lazily: each GEMM stores PRE-BN output + per-channel sum/sumsq;
// the next GEMM applies y = relu(a[c]*x + s[c]) during LDS staging.
// e3 output is never materialized: GEMM accumulates per-(b,o) max/min (BN commutes with max).
// h1 concat-GEMM is decomposed: K=1088 -> (512x1024x32 micro GEMM on g) + K=64 GEMM on pointfeat.

#define M_TOTAL 65536
#define BN_EPS 1e-5f
#define W_THRESH 1e-4f

// ---- order-preserving float <-> uint keys (for atomic max; min via max of key(-x)) ----
__device__ __forceinline__ unsigned fkey(float f) {
    unsigned u = __float_as_uint(f);
    return (u & 0x80000000u) ? ~u : (u | 0x80000000u);
}
__device__ __forceinline__ float fkey_dec(unsigned k) {
    unsigned u = (k & 0x80000000u) ? (k & 0x7FFFFFFFu) : ~k;
    return __uint_as_float(u);
}

// ---- zero stats / keys / counters (ws is poisoned 0xAA before every call) ----
__global__ void k_init(float* sums, float* sumsqs, unsigned* kmax, unsigned* kminneg, int* nv) {
    int i = blockIdx.x * 256 + threadIdx.x;
    if (i < 2112) { sums[i] = 0.f; sumsqs[i] = 0.f; }
    if (i < 32768) { kmax[i] = 0u; kminneg[i] = 0u; }
    if (i < 32) nv[i] = 0;
}

// ---- layer e1: 3 -> 64, reads points directly, writes pre-BN Y1e + stats ----
__global__ void k_e1(const float* __restrict__ pts, const float* __restrict__ w,
                     const float* __restrict__ bias, float* __restrict__ Y,
                     float* __restrict__ sum, float* __restrict__ sumsq) {
    int o = blockIdx.y;
    int m = blockIdx.x * 256 + threadIdx.x;
    int b = m >> 11, n = m & 2047;
    const float* p = pts + b * 6144 + n;
    float v = fmaf(w[o * 3 + 0], p[0],
              fmaf(w[o * 3 + 1], p[2048],
              fmaf(w[o * 3 + 2], p[4096], bias[o])));
    Y[o * M_TOTAL + m] = v;
    float s = v, ss = v * v;
    for (int off = 32; off; off >>= 1) {
        s += __shfl_down(s, off);
        ss += __shfl_down(ss, off);
    }
    __shared__ float ls[4], lss[4];
    int lane = threadIdx.x & 63, wv = threadIdx.x >> 6;
    if (lane == 0) { ls[wv] = s; lss[wv] = ss; }
    __syncthreads();
    if (threadIdx.x == 0) {
        atomicAdd(&sum[o], ls[0] + ls[1] + ls[2] + ls[3]);
        atomicAdd(&sumsq[o], lss[0] + lss[1] + lss[2] + lss[3]);
    }
}

// ---- per-channel BN finalize: (sum,sumsq,gamma,beta) -> (a, s) with y = a*x + s ----
__global__ void k_finalize(const float* __restrict__ sum, const float* __restrict__ sumsq,
                           const float* __restrict__ g, const float* __restrict__ be,
                           float* __restrict__ a, float* __restrict__ s, int C) {
    int c = blockIdx.x * 64 + threadIdx.x;
    if (c >= C) return;
    float mean = sum[c] * (1.f / M_TOTAL);
    float var = sumsq[c] * (1.f / M_TOTAL) - mean * mean;
    float rstd = rsqrtf(var + BN_EPS);
    float ac = g[c] * rstd;
    a[c] = ac;
    s[c] = be[c] - mean * ac;
}

// ---- generic fused GEMM: Y[o][m] = bias + sum_c W[o*ldw+c] * relu(a[c]*X[c][m]+s[c]) ----
// 64x64 tile, BK=16, 256 threads, 4x4 micro-tile. Always accumulates per-channel stats.
// MINMAX: also per-(b,o) max/min atomics (e3). BIAS_BO: bias indexed [b*O+o] (h1 uses Gh).
template <bool STORE, bool MINMAX, bool BIAS_BO>
__launch_bounds__(256)
__global__ void k_gemm(const float* __restrict__ W, int ldw, int K, int O,
                       const float* __restrict__ X,
                       const float* __restrict__ a_in, const float* __restrict__ s_in,
                       const float* __restrict__ bias,
                       float* __restrict__ Y,
                       float* __restrict__ sum, float* __restrict__ sumsq,
                       unsigned* __restrict__ kmax, unsigned* __restrict__ kminneg) {
    __shared__ float sW[16][64];
    __shared__ float sX[16][64];
    int tid = threadIdx.x;
    int tx = tid & 15, ty = tid >> 4;
    int m0 = blockIdx.x * 64;
    int o0 = blockIdx.y * 64;
    int ow = tid >> 2, c4 = (tid & 3) * 4;
    float acc[4][4] = {};

    for (int k0 = 0; k0 < K; k0 += 16) {
        {   // X tile: row kk = ty (16 rows), 16 lanes * float4 = 64 cols, BN+ReLU on load
            int kk = ty, j = tx * 4;
            float a = a_in[k0 + kk], s = s_in[k0 + kk];
            float4 xv = *(const float4*)(X + (size_t)(k0 + kk) * M_TOTAL + m0 + j);
            xv.x = fmaxf(fmaf(a, xv.x, s), 0.f);
            xv.y = fmaxf(fmaf(a, xv.y, s), 0.f);
            xv.z = fmaxf(fmaf(a, xv.z, s), 0.f);
            xv.w = fmaxf(fmaf(a, xv.w, s), 0.f);
            *(float4*)&sX[kk][j] = xv;
        }
        {   // W tile: each thread one float4 along K, store transposed [kk][o]
            float4 wv = *(const float4*)(W + (size_t)(o0 + ow) * ldw + k0 + c4);
            sW[c4 + 0][ow] = wv.x;
            sW[c4 + 1][ow] = wv.y;
            sW[c4 + 2][ow] = wv.z;
            sW[c4 + 3][ow] = wv.w;
        }
        __syncthreads();
#pragma unroll
        for (int kk = 0; kk < 16; kk++) {
            float4 wv = *(const float4*)&sW[kk][ty * 4];
            float4 xv = *(const float4*)&sX[kk][tx * 4];
            float wr[4] = {wv.x, wv.y, wv.z, wv.w};
            float xr[4] = {xv.x, xv.y, xv.z, xv.w};
#pragma unroll
            for (int i = 0; i < 4; i++)
#pragma unroll
                for (int j = 0; j < 4; j++)
                    acc[i][j] = fmaf(wr[i], xr[j], acc[i][j]);
        }
        __syncthreads();
    }

    int bidx = m0 >> 11;
#pragma unroll
    for (int i = 0; i < 4; i++) {
        int o = o0 + ty * 4 + i;
        float bv = BIAS_BO ? bias[bidx * O + o] : bias[o];
#pragma unroll
        for (int j = 0; j < 4; j++) acc[i][j] += bv;
    }

    if constexpr (STORE) {
#pragma unroll
        for (int i = 0; i < 4; i++) {
            int o = o0 + ty * 4 + i;
            float4 v = make_float4(acc[i][0], acc[i][1], acc[i][2], acc[i][3]);
            *(float4*)(Y + (size_t)o * M_TOTAL + m0 + tx * 4) = v;
        }
    }

#pragma unroll
    for (int i = 0; i < 4; i++) {
        int o = o0 + ty * 4 + i;
        float s = acc[i][0] + acc[i][1] + acc[i][2] + acc[i][3];
        float ss = acc[i][0] * acc[i][0] + acc[i][1] * acc[i][1] +
                   acc[i][2] * acc[i][2] + acc[i][3] * acc[i][3];
        for (int off = 8; off; off >>= 1) {
            s += __shfl_down(s, off, 16);
            ss += __shfl_down(ss, off, 16);
        }
        if (tx == 0) {
            atomicAdd(&sum[o], s);
            atomicAdd(&sumsq[o], ss);
        }
        if constexpr (MINMAX) {
            float mx = fmaxf(fmaxf(acc[i][0], acc[i][1]), fmaxf(acc[i][2], acc[i][3]));
            float mn = fminf(fminf(acc[i][0], acc[i][1]), fminf(acc[i][2], acc[i][3]));
            for (int off = 8; off; off >>= 1) {
                mx = fmaxf(mx, __shfl_down(mx, off, 16));
                mn = fminf(mn, __shfl_down(mn, off, 16));
            }
            if (tx == 0) {
                atomicMax(&kmax[bidx * O + o], fkey(mx));
                atomicMax(&kminneg[bidx * O + o], fkey(-mn));
            }
        }
    }
}

// ---- g[b][o] = BN3 applied to max (or min if a<0) of e3 pre-act ----
__global__ void k_g(const unsigned* __restrict__ kmax, const unsigned* __restrict__ kminneg,
                    const float* __restrict__ a3, const float* __restrict__ s3,
                    float* __restrict__ g) {
    int i = blockIdx.x * 256 + threadIdx.x;  // i = b*1024 + o
    if (i >= 32768) return;
    int o = i & 1023;
    float mx = fkey_dec(kmax[i]);
    float mn = -fkey_dec(kminneg[i]);
    float a = a3[o];
    g[i] = (a >= 0.f) ? fmaf(a, mx, s3[o]) : fmaf(a, mn, s3[o]);
}

// ---- Gh[b][o] = h_b1[o] + sum_{c<1024} h_w1[o*1088+c] * g[b*1024+c] ----
__global__ void k_gh(const float* __restrict__ hw1, const float* __restrict__ hb1,
                     const float* __restrict__ g, float* __restrict__ Gh) {
    int b = threadIdx.x & 31;
    int o = blockIdx.x * 8 + (threadIdx.x >> 5);
    const float* wr = hw1 + (size_t)o * 1088;
    const float* gr = g + b * 1024;
    float acc = hb1[o];
#pragma unroll 4
    for (int c = 0; c < 1024; c++) acc = fmaf(wr[c], gr[c], acc);
    Gh[b * 512 + o] = acc;
}

// ---- h4: 128 -> 1, weights = 1 + conv + b4; per-batch valid count ----
__global__ void k_h4(const float* __restrict__ Y3, const float* __restrict__ a,
                     const float* __restrict__ s, const float* __restrict__ w4,
                     const float* __restrict__ b4, float* __restrict__ outw,
                     int* __restrict__ nv) {
    int m = blockIdx.x * 256 + threadIdx.x;
    float acc = 0.f;
#pragma unroll 4
    for (int c = 0; c < 128; c++) {
        float x = fmaxf(fmaf(a[c], Y3[(size_t)c * M_TOTAL + m], s[c]), 0.f);
        acc = fmaf(w4[c], x, acc);
    }
    float wgt = 1.f + acc + b4[0];
    outw[m] = wgt;
    unsigned long long msk = __ballot(wgt > W_THRESH);
    __shared__ int cnt[4];
    int lane = threadIdx.x & 63, wv = threadIdx.x >> 6;
    if (lane == 0) cnt[wv] = __popcll(msk);
    __syncthreads();
    if (threadIdx.x == 0) atomicAdd(&nv[m >> 11], cnt[0] + cnt[1] + cnt[2] + cnt[3]);
}

// ---- per-batch weighted least squares + 3x3 Cholesky solve ----
__global__ void k_wls(const float* __restrict__ pts, const float* __restrict__ outw,
                      const int* __restrict__ nv, float* __restrict__ beta) {
    int b = blockIdx.x;
    const float* p = pts + b * 6144;
    const float* wr = outw + b * 2048;
    bool use_w = nv[b] > 3;
    float s[9] = {0, 0, 0, 0, 0, 0, 0, 0, 0};
    for (int n = threadIdx.x; n < 2048; n += 256) {
        float wgt = wr[n];
        float we = use_w ? (wgt > W_THRESH ? wgt : 0.f) : 1.f;
        float px = p[n], py = p[2048 + n], pz = p[4096 + n];
        s[0] += we * px * px; s[1] += we * px * py; s[2] += we * px;
        s[3] += we * py * py; s[4] += we * py;      s[5] += we;
        s[6] += we * px * pz; s[7] += we * py * pz; s[8] += we * pz;
    }
    for (int off = 32; off; off >>= 1)
#pragma unroll
        for (int i = 0; i < 9; i++) s[i] += __shfl_down(s[i], off);
    __shared__ float red[4][9];
    int lane = threadIdx.x & 63, wv = threadIdx.x >> 6;
    if (lane == 0)
        for (int i = 0; i < 9; i++) red[wv][i] = s[i];
    __syncthreads();
    if (threadIdx.x == 0) {
        float t[9];
        for (int i = 0; i < 9; i++) t[i] = red[0][i] + red[1][i] + red[2][i] + red[3][i];
        float a11 = t[0], a21 = t[1], a31 = t[2], a22 = t[3], a32 = t[4], a33 = t[5];
        float L11 = sqrtf(a11);
        float L21 = a21 / L11, L31 = a31 / L11;
        float L22 = sqrtf(a22 - L21 * L21);
        float L32 = (a32 - L31 * L21) / L22;
        float L33 = sqrtf(a33 - L31 * L31 - L32 * L32);
        float u1 = t[6] / L11;
        float u2 = (t[7] - L21 * u1) / L22;
        float u3 = (t[8] - L31 * u1 - L32 * u2) / L33;
        float b3 = u3 / L33;
        float b2 = (u2 - L32 * b3) / L22;
        float b1 = (u1 - L21 * b2 - L31 * b3) / L11;
        beta[b * 3 + 0] = b1;
        beta[b * 3 + 1] = b2;
        beta[b * 3 + 2] = b3;
    }
}

extern "C" void kernel_launch(void* const* d_in, const int* in_sizes, int n_in,
                              void* d_out, int out_size, void* d_ws, size_t ws_size,
                              hipStream_t stream) {
    (void)in_sizes; (void)n_in; (void)out_size; (void)ws_size;
    const float* pts   = (const float*)d_in[0];
    const float* e_w1  = (const float*)d_in[1];
    const float* e_b1  = (const float*)d_in[2];
    const float* e_g1  = (const float*)d_in[3];
    const float* e_be1 = (const float*)d_in[4];
    const float* e_w2  = (const float*)d_in[5];
    const float* e_b2  = (const float*)d_in[6];
    const float* e_g2  = (const float*)d_in[7];
    const float* e_be2 = (const float*)d_in[8];
    const float* e_w3  = (const float*)d_in[9];
    const float* e_b3  = (const float*)d_in[10];
    const float* e_g3  = (const float*)d_in[11];
    const float* e_be3 = (const float*)d_in[12];
    const float* h_w1  = (const float*)d_in[13];
    const float* h_b1  = (const float*)d_in[14];
    const float* h_g1  = (const float*)d_in[15];
    const float* h_be1 = (const float*)d_in[16];
    const float* h_w2  = (const float*)d_in[17];
    const float* h_b2  = (const float*)d_in[18];
    const float* h_g2  = (const float*)d_in[19];
    const float* h_be2 = (const float*)d_in[20];
    const float* h_w3  = (const float*)d_in[21];
    const float* h_b3  = (const float*)d_in[22];
    const float* h_g3  = (const float*)d_in[23];
    const float* h_be3 = (const float*)d_in[24];
    const float* h_w4  = (const float*)d_in[25];
    const float* h_b4  = (const float*)d_in[26];

    const size_t M = M_TOTAL;
    float* wsf = (float*)d_ws;
    // Buffer plan (aliased; peak ~219 MB):
    //   Y1e [64*M]  alive e1 .. h1
    //   BIG [512*M] holds Y2e (e2..e3), then Y1h (h1..h2), then Y3h (h3..h4)
    //   Y2h [256*M] alive h2 .. h3
    float* Y1e = wsf;
    float* BIG = wsf + 64 * M;
    float* Y2h = BIG + 512 * M;
    float* sums   = Y2h + 256 * M;   // 2112 channels total: e1@0 e2@64 e3@192 h1@1216 h2@1728 h3@1984
    float* sumsqs = sums + 2112;
    float* avec   = sumsqs + 2112;
    float* svec   = avec + 2112;
    unsigned* kmax = (unsigned*)(svec + 2112);   // [32][1024]
    unsigned* kmin = kmax + 32768;               // keys of (-x): min via max
    float* gbuf = (float*)(kmin + 32768);        // [32][1024]
    float* Gh   = gbuf + 32768;                  // [32][512]
    int* nv     = (int*)(Gh + 16384);            // [32]

    float* beta = (float*)d_out;      // [32][3]
    float* outw = beta + 96;          // [32][2048]

    float* Y2e = BIG;
    float* Y1h = BIG;
    float* Y3h = BIG;

    k_init<<<128, 256, 0, stream>>>(sums, sumsqs, kmax, kmin, nv);

    // e1: 3 -> 64
    k_e1<<<dim3(256, 64), 256, 0, stream>>>(pts, e_w1, e_b1, Y1e, sums + 0, sumsqs + 0);
    k_finalize<<<1, 64, 0, stream>>>(sums + 0, sumsqs + 0, e_g1, e_be1, avec + 0, svec + 0, 64);

    // e2: 64 -> 128
    k_gemm<true, false, false><<<dim3(1024, 2), 256, 0, stream>>>(
        e_w2, 64, 64, 128, Y1e, avec + 0, svec + 0, e_b2, Y2e,
        sums + 64, sumsqs + 64, nullptr, nullptr);
    k_finalize<<<2, 64, 0, stream>>>(sums + 64, sumsqs + 64, e_g2, e_be2, avec + 64, svec + 64, 128);

    // e3: 128 -> 1024, no store, stats + per-(b,o) max/min
    k_gemm<false, true, false><<<dim3(1024, 16), 256, 0, stream>>>(
        e_w3, 128, 128, 1024, Y2e, avec + 64, svec + 64, e_b3, nullptr,
        sums + 192, sumsqs + 192, kmax, kmin);
    k_finalize<<<16, 64, 0, stream>>>(sums + 192, sumsqs + 192, e_g3, e_be3, avec + 192, svec + 192, 1024);

    // g = BN3(max), then Gh = h_w1[:, :1024] @ g + h_b1
    k_g<<<128, 256, 0, stream>>>(kmax, kmin, avec + 192, svec + 192, gbuf);
    k_gh<<<64, 256, 0, stream>>>(h_w1, h_b1, gbuf, Gh);

    // h1: pointfeat part, K=64, bias = Gh[b][o]
    k_gemm<true, false, true><<<dim3(1024, 8), 256, 0, stream>>>(
        h_w1 + 1024, 1088, 64, 512, Y1e, avec + 0, svec + 0, Gh, Y1h,
        sums + 1216, sumsqs + 1216, nullptr, nullptr);
    k_finalize<<<8, 64, 0, stream>>>(sums + 1216, sumsqs + 1216, h_g1, h_be1, avec + 1216, svec + 1216, 512);

    // h2: 512 -> 256
    k_gemm<true, false, false><<<dim3(1024, 4), 256, 0, stream>>>(
        h_w2, 512, 512, 256, Y1h, avec + 1216, svec + 1216, h_b2, Y2h,
        sums + 1728, sumsqs + 1728, nullptr, nullptr);
    k_finalize<<<4, 64, 0, stream>>>(sums + 1728, sumsqs + 1728, h_g2, h_be2, avec + 1728, svec + 1728, 256);

    // h3: 256 -> 128 (writes over dead Y1h region)
    k_gemm<true, false, false><<<dim3(1024, 2), 256, 0, stream>>>(
        h_w3, 256, 256, 128, Y2h, avec + 1728, svec + 1728, h_b3, Y3h,
        sums + 1984, sumsqs + 1984, nullptr, nullptr);
    k_finalize<<<2, 64, 0, stream>>>(sums + 1984, sumsqs + 1984, h_g3, h_be3, avec + 1984, svec + 1984, 128);

    // h4 -> weights (+ valid counts), then per-batch WLS solve -> beta
    k_h4<<<256, 256, 0, stream>>>(Y3h, avec + 1984, svec + 1984, h_w4, h_b4, outw, nv);
    k_wls<<<32, 256, 0, stream>>>(pts, outw, nv, beta);
}

// Round 3
// 1492.413 us; speedup vs baseline: 1.2993x; 1.2993x over previous
//
#include <hip/hip_runtime.h>
#include <math.h>

// SimpPointNet fused pipeline, round 3: fp16 MFMA GEMMs (bf16 was 1.26x over threshold),
// point-major [M][C] activations. M = B*N = 65536, m = b*2048 + n.
// Activations stored PRE-BN as fp16 [M][C]; BN+ReLU applied in fp32 during LDS staging.
// e3 never materialized (per-(b,o) max/min atomics; BN commutes with max).
// h1 concat-GEMM decomposed: K=1088 -> (512x1024x32 on g, fp32) + K=64 GEMM on pointfeat.
// e1 BN stats computed analytically from point second moments.

#define M_TOTAL 65536
#define BN_EPS 1e-5f
#define W_THRESH 1e-4f

typedef __attribute__((ext_vector_type(8))) _Float16 f16x8;
typedef __attribute__((ext_vector_type(4))) float f32x4;

__device__ __forceinline__ unsigned short f2h(float f) {
    _Float16 h = (_Float16)f;  // v_cvt_f16_f32, RNE
    return __builtin_bit_cast(unsigned short, h);
}
__device__ __forceinline__ float h2f(unsigned short u) {
    return (float)__builtin_bit_cast(_Float16, u);
}

// ---- order-preserving float <-> uint keys (atomic max; min via max of key(-x)) ----
__device__ __forceinline__ unsigned fkey(float f) {
    unsigned u = __float_as_uint(f);
    return (u & 0x80000000u) ? ~u : (u | 0x80000000u);
}
__device__ __forceinline__ float fkey_dec(unsigned k) {
    unsigned u = (k & 0x80000000u) ? (k & 0x7FFFFFFFu) : ~k;
    return __uint_as_float(u);
}

// ---- zero stats / keys / counters / moments ----
__global__ void k_init(float* sums, float* sumsqs, unsigned* kmax, unsigned* kminneg,
                       int* nv, float* mom) {
    int i = blockIdx.x * 256 + threadIdx.x;
    if (i < 2112) { sums[i] = 0.f; sumsqs[i] = 0.f; }
    if (i < 32768) { kmax[i] = 0u; kminneg[i] = 0u; }
    if (i < 32) nv[i] = 0;
    if (i < 12) mom[i] = 0.f;
}

// ---- point second moments over all 65536 pts ----
__global__ void k_moments(const float* __restrict__ pts, float* __restrict__ mom) {
    float s[9] = {0,0,0,0,0,0,0,0,0};
    for (int m = blockIdx.x * 256 + threadIdx.x; m < M_TOTAL; m += gridDim.x * 256) {
        int b = m >> 11, n = m & 2047;
        const float* p = pts + b * 6144 + n;
        float x = p[0], y = p[2048], z = p[4096];
        s[0] += x; s[1] += y; s[2] += z;
        s[3] += x * x; s[4] += y * y; s[5] += z * z;
        s[6] += x * y; s[7] += x * z; s[8] += y * z;
    }
    for (int off = 32; off; off >>= 1)
#pragma unroll
        for (int i = 0; i < 9; i++) s[i] += __shfl_down(s[i], off);
    __shared__ float red[4][9];
    int lane = threadIdx.x & 63, wv = threadIdx.x >> 6;
    if (lane == 0)
        for (int i = 0; i < 9; i++) red[wv][i] = s[i];
    __syncthreads();
    if (threadIdx.x < 9)
        atomicAdd(&mom[threadIdx.x],
                  red[0][threadIdx.x] + red[1][threadIdx.x] + red[2][threadIdx.x] + red[3][threadIdx.x]);
}

// ---- e1 BN params analytically from moments ----
__global__ void k_e1fin(const float* __restrict__ mom, const float* __restrict__ w,
                        const float* __restrict__ bias, const float* __restrict__ g,
                        const float* __restrict__ be, float* __restrict__ a, float* __restrict__ s) {
    int o = threadIdx.x;  // 64
    float w0 = w[o * 3], w1 = w[o * 3 + 1], w2 = w[o * 3 + 2], b = bias[o];
    float wS1 = w0 * mom[0] + w1 * mom[1] + w2 * mom[2];
    float sum = wS1 + 65536.f * b;
    float sumsq = w0 * w0 * mom[3] + w1 * w1 * mom[4] + w2 * w2 * mom[5]
                + 2.f * (w0 * w1 * mom[6] + w0 * w2 * mom[7] + w1 * w2 * mom[8])
                + 2.f * b * wS1 + 65536.f * b * b;
    float mean = sum * (1.f / 65536.f);
    float var = sumsq * (1.f / 65536.f) - mean * mean;
    float ac = g[o] * rsqrtf(var + BN_EPS);
    a[o] = ac;
    s[o] = be[o] - mean * ac;
}

// ---- e1: 3 -> 64, point-major fp16 output [M][64] ----
__global__ void k_e1(const float* __restrict__ pts, const float* __restrict__ w,
                     const float* __restrict__ bias, unsigned short* __restrict__ Y) {
    __shared__ float wl[192], bl[64];
    int tid = threadIdx.x;
    if (tid < 192) wl[tid] = w[tid];
    if (tid < 64) bl[tid] = bias[tid];
    __syncthreads();
    int m = blockIdx.x * 256 + tid;
    int b = m >> 11, n = m & 2047;
    const float* p = pts + b * 6144 + n;
    float px = p[0], py = p[2048], pz = p[4096];
    unsigned short* yr = Y + (size_t)m * 64;
#pragma unroll
    for (int o8 = 0; o8 < 64; o8 += 8) {
        uint4 pk;
        unsigned pkw[4];
#pragma unroll
        for (int t = 0; t < 4; t++) {
            int o = o8 + t * 2;
            float v0 = fmaf(wl[o * 3 + 0], px, fmaf(wl[o * 3 + 1], py, fmaf(wl[o * 3 + 2], pz, bl[o])));
            float v1 = fmaf(wl[o * 3 + 3], px, fmaf(wl[o * 3 + 4], py, fmaf(wl[o * 3 + 5], pz, bl[o + 1])));
            pkw[t] = (unsigned)f2h(v0) | ((unsigned)f2h(v1) << 16);
        }
        pk.x = pkw[0]; pk.y = pkw[1]; pk.z = pkw[2]; pk.w = pkw[3];
        *(uint4*)(yr + o8) = pk;
    }
}

// ---- per-channel BN finalize ----
__global__ void k_finalize(const float* __restrict__ sum, const float* __restrict__ sumsq,
                           const float* __restrict__ g, const float* __restrict__ be,
                           float* __restrict__ a, float* __restrict__ s, int C) {
    int c = blockIdx.x * 64 + threadIdx.x;
    if (c >= C) return;
    float mean = sum[c] * (1.f / M_TOTAL);
    float var = sumsq[c] * (1.f / M_TOTAL) - mean * mean;
    float rstd = rsqrtf(var + BN_EPS);
    float ac = g[c] * rstd;
    a[c] = ac;
    s[c] = be[c] - mean * ac;
}

// ---- MFMA GEMM: Y[m][o] = bias + sum_k Whf[o][k] * relu(a[k]*X[m][k]+s[k]) ----
// Block tile: 128 o x 128 m, BK=32, 4 waves (2x2), each wave 4x4 tiles of 16x16x32 f16.
// LDS tiles in fragment order: [tile][lane][8 f16], contiguous 16B per lane.
template <bool STORE, bool MINMAX, bool BIAS_BO>
__launch_bounds__(256, 2)
__global__ void k_mgemm(const float* __restrict__ W, int ldw, int K, int O,
                        const unsigned short* __restrict__ X,
                        const float* __restrict__ a_in, const float* __restrict__ s_in,
                        const float* __restrict__ bias,
                        unsigned short* __restrict__ Y,
                        float* __restrict__ sum, float* __restrict__ sumsq,
                        unsigned* __restrict__ kmax, unsigned* __restrict__ kminneg) {
    __shared__ __align__(16) short sA[4096];   // 8 o-tiles x 64 lanes x 8 f16
    __shared__ __align__(16) short sB[4096];   // 8 m-tiles x 64 lanes x 8 f16
    __shared__ float sa[512], ssh[512];
    int tid = threadIdx.x;
    int lane = tid & 63, wave = tid >> 6;
    int wo = wave >> 1, wm = wave & 1;
    int m0 = blockIdx.x * 128, o0 = blockIdx.y * 128;

    for (int c = tid; c < K; c += 256) { sa[c] = a_in[c]; ssh[c] = s_in[c]; }

    f32x4 zero = {0.f, 0.f, 0.f, 0.f};
    f32x4 acc[4][4];
#pragma unroll
    for (int i = 0; i < 4; i++)
#pragma unroll
        for (int j = 0; j < 4; j++) acc[i][j] = zero;

    __syncthreads();

    for (int k0 = 0; k0 < K; k0 += 32) {
        // stage A (weights fp32 -> fp16, frag order)
#pragma unroll
        for (int c = tid; c < 512; c += 256) {
            int oi = c >> 2, kc = c & 3;
            const float* wp = W + (size_t)(o0 + oi) * ldw + k0 + kc * 8;
            float4 wa = *(const float4*)wp;
            float4 wb = *(const float4*)(wp + 4);
            uint4 pk;
            pk.x = (unsigned)f2h(wa.x) | ((unsigned)f2h(wa.y) << 16);
            pk.y = (unsigned)f2h(wa.z) | ((unsigned)f2h(wa.w) << 16);
            pk.z = (unsigned)f2h(wb.x) | ((unsigned)f2h(wb.y) << 16);
            pk.w = (unsigned)f2h(wb.z) | ((unsigned)f2h(wb.w) << 16);
            *(uint4*)&sA[((oi >> 4) * 64 + (oi & 15) + kc * 16) * 8] = pk;
        }
        // stage B (fp16 X -> BN+ReLU in fp32 -> fp16, frag order)
#pragma unroll
        for (int c = tid; c < 512; c += 256) {
            int mi = c >> 2, kc = c & 3;
            const unsigned short* xp = X + (size_t)(m0 + mi) * K + k0 + kc * 8;
            uint4 raw = *(const uint4*)xp;
            unsigned u[4] = {raw.x, raw.y, raw.z, raw.w};
            int kb = k0 + kc * 8;
            unsigned pkw[4];
#pragma unroll
            for (int t = 0; t < 4; t++) {
                float x0 = h2f((unsigned short)(u[t] & 0xffffu));
                float x1 = h2f((unsigned short)(u[t] >> 16));
                float y0 = fmaxf(fmaf(sa[kb + t * 2], x0, ssh[kb + t * 2]), 0.f);
                float y1 = fmaxf(fmaf(sa[kb + t * 2 + 1], x1, ssh[kb + t * 2 + 1]), 0.f);
                pkw[t] = (unsigned)f2h(y0) | ((unsigned)f2h(y1) << 16);
            }
            uint4 pk; pk.x = pkw[0]; pk.y = pkw[1]; pk.z = pkw[2]; pk.w = pkw[3];
            *(uint4*)&sB[((mi >> 4) * 64 + (mi & 15) + kc * 16) * 8] = pk;
        }
        __syncthreads();
        f16x8 af[4], bfr[4];
#pragma unroll
        for (int i = 0; i < 4; i++)
            af[i] = *(const f16x8*)&sA[((wo * 4 + i) * 64 + lane) * 8];
#pragma unroll
        for (int j = 0; j < 4; j++)
            bfr[j] = *(const f16x8*)&sB[((wm * 4 + j) * 64 + lane) * 8];
#pragma unroll
        for (int i = 0; i < 4; i++)
#pragma unroll
            for (int j = 0; j < 4; j++)
                acc[i][j] = __builtin_amdgcn_mfma_f32_16x16x32_f16(af[i], bfr[j], acc[i][j], 0, 0, 0);
        __syncthreads();
    }

    // epilogue: C/D layout col(=m)=lane&15, row(=o within tile)=quad*4+reg
    int q = lane >> 4, lc = lane & 15;
    int bidx = m0 >> 11;
#pragma unroll
    for (int i = 0; i < 4; i++) {
        int ob = o0 + wo * 64 + i * 16 + q * 4;
        float bv[4];
#pragma unroll
        for (int r = 0; r < 4; r++)
            bv[r] = BIAS_BO ? bias[bidx * O + ob + r] : bias[ob + r];
        float s4[4] = {0, 0, 0, 0}, q4[4] = {0, 0, 0, 0};
        float mx[4], mn[4];
        if constexpr (MINMAX) {
#pragma unroll
            for (int r = 0; r < 4; r++) { mx[r] = -3.4e38f; mn[r] = 3.4e38f; }
        }
#pragma unroll
        for (int j = 0; j < 4; j++) {
            int m = m0 + wm * 64 + j * 16 + lc;
            float v[4];
#pragma unroll
            for (int r = 0; r < 4; r++) {
                v[r] = acc[i][j][r] + bv[r];
                s4[r] += v[r];
                q4[r] += v[r] * v[r];
                if constexpr (MINMAX) { mx[r] = fmaxf(mx[r], v[r]); mn[r] = fminf(mn[r], v[r]); }
            }
            if constexpr (STORE) {
                uint2 pk;
                pk.x = (unsigned)f2h(v[0]) | ((unsigned)f2h(v[1]) << 16);
                pk.y = (unsigned)f2h(v[2]) | ((unsigned)f2h(v[3]) << 16);
                *(uint2*)(Y + (size_t)m * O + ob) = pk;
            }
        }
#pragma unroll
        for (int off = 1; off < 16; off <<= 1) {
#pragma unroll
            for (int r = 0; r < 4; r++) {
                s4[r] += __shfl_xor(s4[r], off);
                q4[r] += __shfl_xor(q4[r], off);
                if constexpr (MINMAX) {
                    mx[r] = fmaxf(mx[r], __shfl_xor(mx[r], off));
                    mn[r] = fminf(mn[r], __shfl_xor(mn[r], off));
                }
            }
        }
        if (lc == 0) {
#pragma unroll
            for (int r = 0; r < 4; r++) {
                atomicAdd(&sum[ob + r], s4[r]);
                atomicAdd(&sumsq[ob + r], q4[r]);
                if constexpr (MINMAX) {
                    atomicMax(&kmax[bidx * O + ob + r], fkey(mx[r]));
                    atomicMax(&kminneg[bidx * O + ob + r], fkey(-mn[r]));
                }
            }
        }
    }
}

// ---- g[b][o] = BN3 applied to max (or min if a<0) of e3 pre-act ----
__global__ void k_g(const unsigned* __restrict__ kmax, const unsigned* __restrict__ kminneg,
                    const float* __restrict__ a3, const float* __restrict__ s3,
                    float* __restrict__ g) {
    int i = blockIdx.x * 256 + threadIdx.x;  // i = b*1024 + o
    if (i >= 32768) return;
    int o = i & 1023;
    float mx = fkey_dec(kmax[i]);
    float mn = -fkey_dec(kminneg[i]);
    float a = a3[o];
    g[i] = (a >= 0.f) ? fmaf(a, mx, s3[o]) : fmaf(a, mn, s3[o]);
}

// ---- Gh[b][o] = h_b1[o] + sum_{c<1024} h_w1[o*1088+c] * g[b*1024+c] (fp32 exact) ----
__global__ void k_gh(const float* __restrict__ hw1, const float* __restrict__ hb1,
                     const float* __restrict__ g, float* __restrict__ Gh) {
    int b = threadIdx.x & 31;
    int o = blockIdx.x * 8 + (threadIdx.x >> 5);
    const float* wr = hw1 + (size_t)o * 1088;
    const float* gr = g + b * 1024;
    float acc = hb1[o];
#pragma unroll 4
    for (int c = 0; c < 1024; c++) acc = fmaf(wr[c], gr[c], acc);
    Gh[b * 512 + o] = acc;
}

// ---- h4: 128 -> 1 on [M][128] fp16; weights = 1 + conv + b4; per-batch valid count ----
__global__ void k_h4(const unsigned short* __restrict__ X, const float* __restrict__ a,
                     const float* __restrict__ s, const float* __restrict__ w4,
                     const float* __restrict__ b4, float* __restrict__ outw,
                     int* __restrict__ nv) {
    __shared__ float la[128], ls[128], lw[128];
    int tid = threadIdx.x;
    if (tid < 128) { la[tid] = a[tid]; ls[tid] = s[tid]; lw[tid] = w4[tid]; }
    __syncthreads();
    int m = blockIdx.x * 256 + tid;
    const unsigned short* xr = X + (size_t)m * 128;
    float acc = 0.f;
#pragma unroll
    for (int c = 0; c < 128; c += 8) {
        uint4 raw = *(const uint4*)(xr + c);
        unsigned u[4] = {raw.x, raw.y, raw.z, raw.w};
#pragma unroll
        for (int t = 0; t < 4; t++) {
            float x0 = h2f((unsigned short)(u[t] & 0xffffu));
            float x1 = h2f((unsigned short)(u[t] >> 16));
            float y0 = fmaxf(fmaf(la[c + t * 2], x0, ls[c + t * 2]), 0.f);
            float y1 = fmaxf(fmaf(la[c + t * 2 + 1], x1, ls[c + t * 2 + 1]), 0.f);
            acc = fmaf(lw[c + t * 2], y0, acc);
            acc = fmaf(lw[c + t * 2 + 1], y1, acc);
        }
    }
    float wgt = 1.f + acc + b4[0];
    outw[m] = wgt;
    unsigned long long msk = __ballot(wgt > W_THRESH);
    __shared__ int cnt[4];
    int lane = threadIdx.x & 63, wv = threadIdx.x >> 6;
    if (lane == 0) cnt[wv] = __popcll(msk);
    __syncthreads();
    if (threadIdx.x == 0) atomicAdd(&nv[m >> 11], cnt[0] + cnt[1] + cnt[2] + cnt[3]);
}

// ---- per-batch weighted least squares + 3x3 Cholesky solve ----
__global__ void k_wls(const float* __restrict__ pts, const float* __restrict__ outw,
                      const int* __restrict__ nv, float* __restrict__ beta) {
    int b = blockIdx.x;
    const float* p = pts + b * 6144;
    const float* wr = outw + b * 2048;
    bool use_w = nv[b] > 3;
    float s[9] = {0, 0, 0, 0, 0, 0, 0, 0, 0};
    for (int n = threadIdx.x; n < 2048; n += 256) {
        float wgt = wr[n];
        float we = use_w ? (wgt > W_THRESH ? wgt : 0.f) : 1.f;
        float px = p[n], py = p[2048 + n], pz = p[4096 + n];
        s[0] += we * px * px; s[1] += we * px * py; s[2] += we * px;
        s[3] += we * py * py; s[4] += we * py;      s[5] += we;
        s[6] += we * px * pz; s[7] += we * py * pz; s[8] += we * pz;
    }
    for (int off = 32; off; off >>= 1)
#pragma unroll
        for (int i = 0; i < 9; i++) s[i] += __shfl_down(s[i], off);
    __shared__ float red[4][9];
    int lane = threadIdx.x & 63, wv = threadIdx.x >> 6;
    if (lane == 0)
        for (int i = 0; i < 9; i++) red[wv][i] = s[i];
    __syncthreads();
    if (threadIdx.x == 0) {
        float t[9];
        for (int i = 0; i < 9; i++) t[i] = red[0][i] + red[1][i] + red[2][i] + red[3][i];
        float a11 = t[0], a21 = t[1], a31 = t[2], a22 = t[3], a32 = t[4], a33 = t[5];
        float L11 = sqrtf(a11);
        float L21 = a21 / L11, L31 = a31 / L11;
        float L22 = sqrtf(a22 - L21 * L21);
        float L32 = (a32 - L31 * L21) / L22;
        float L33 = sqrtf(a33 - L31 * L31 - L32 * L32);
        float u1 = t[6] / L11;
        float u2 = (t[7] - L21 * u1) / L22;
        float u3 = (t[8] - L31 * u1 - L32 * u2) / L33;
        float b3 = u3 / L33;
        float b2 = (u2 - L32 * b3) / L22;
        float b1 = (u1 - L21 * b2 - L31 * b3) / L11;
        beta[b * 3 + 0] = b1;
        beta[b * 3 + 1] = b2;
        beta[b * 3 + 2] = b3;
    }
}

extern "C" void kernel_launch(void* const* d_in, const int* in_sizes, int n_in,
                              void* d_out, int out_size, void* d_ws, size_t ws_size,
                              hipStream_t stream) {
    (void)in_sizes; (void)n_in; (void)out_size; (void)ws_size;
    const float* pts   = (const float*)d_in[0];
    const float* e_w1  = (const float*)d_in[1];
    const float* e_b1  = (const float*)d_in[2];
    const float* e_g1  = (const float*)d_in[3];
    const float* e_be1 = (const float*)d_in[4];
    const float* e_w2  = (const float*)d_in[5];
    const float* e_b2  = (const float*)d_in[6];
    const float* e_g2  = (const float*)d_in[7];
    const float* e_be2 = (const float*)d_in[8];
    const float* e_w3  = (const float*)d_in[9];
    const float* e_b3  = (const float*)d_in[10];
    const float* e_g3  = (const float*)d_in[11];
    const float* e_be3 = (const float*)d_in[12];
    const float* h_w1  = (const float*)d_in[13];
    const float* h_b1  = (const float*)d_in[14];
    const float* h_g1  = (const float*)d_in[15];
    const float* h_be1 = (const float*)d_in[16];
    const float* h_w2  = (const float*)d_in[17];
    const float* h_b2  = (const float*)d_in[18];
    const float* h_g2  = (const float*)d_in[19];
    const float* h_be2 = (const float*)d_in[20];
    const float* h_w3  = (const float*)d_in[21];
    const float* h_b3  = (const float*)d_in[22];
    const float* h_g3  = (const float*)d_in[23];
    const float* h_be3 = (const float*)d_in[24];
    const float* h_w4  = (const float*)d_in[25];
    const float* h_b4  = (const float*)d_in[26];

    const size_t M = M_TOTAL;
    unsigned short* wsu = (unsigned short*)d_ws;
    // fp16 activations, point-major [M][C]:
    unsigned short* Y1e = wsu;             // [M][64]
    unsigned short* Y2e = wsu + 64 * M;    // [M][128]
    unsigned short* Y1h = wsu + 192 * M;   // [M][512]
    unsigned short* Y2h = wsu + 704 * M;   // [M][256]
    unsigned short* Y3h = wsu + 960 * M;   // [M][128]
    float* wsf = (float*)(wsu + 1088 * M);
    float* sums   = wsf;                   // 2112 ch: e1@0 e2@64 e3@192 h1@1216 h2@1728 h3@1984
    float* sumsqs = sums + 2112;
    float* avec   = sumsqs + 2112;
    float* svec   = avec + 2112;
    float* mom    = svec + 2112;           // 12
    unsigned* kmax = (unsigned*)(mom + 12);    // [32][1024]
    unsigned* kmin = kmax + 32768;
    float* gbuf = (float*)(kmin + 32768);      // [32][1024]
    float* Gh   = gbuf + 32768;                // [32][512]
    int* nv     = (int*)(Gh + 16384);          // [32]

    float* beta = (float*)d_out;      // [32][3]
    float* outw = beta + 96;          // [32][2048]

    k_init<<<128, 256, 0, stream>>>(sums, sumsqs, kmax, kmin, nv, mom);

    // e1: 3 -> 64 (+ analytic BN stats from point moments)
    k_moments<<<64, 256, 0, stream>>>(pts, mom);
    k_e1<<<256, 256, 0, stream>>>(pts, e_w1, e_b1, Y1e);
    k_e1fin<<<1, 64, 0, stream>>>(mom, e_w1, e_b1, e_g1, e_be1, avec + 0, svec + 0);

    // e2: 64 -> 128
    k_mgemm<true, false, false><<<dim3(512, 1), 256, 0, stream>>>(
        e_w2, 64, 64, 128, Y1e, avec + 0, svec + 0, e_b2, Y2e,
        sums + 64, sumsqs + 64, nullptr, nullptr);
    k_finalize<<<2, 64, 0, stream>>>(sums + 64, sumsqs + 64, e_g2, e_be2, avec + 64, svec + 64, 128);

    // e3: 128 -> 1024, no store, stats + per-(b,o) max/min
    k_mgemm<false, true, false><<<dim3(512, 8), 256, 0, stream>>>(
        e_w3, 128, 128, 1024, Y2e, avec + 64, svec + 64, e_b3, nullptr,
        sums + 192, sumsqs + 192, kmax, kmin);
    k_finalize<<<16, 64, 0, stream>>>(sums + 192, sumsqs + 192, e_g3, e_be3, avec + 192, svec + 192, 1024);

    // g = BN3(max), then Gh = h_w1[:, :1024] @ g + h_b1
    k_g<<<128, 256, 0, stream>>>(kmax, kmin, avec + 192, svec + 192, gbuf);
    k_gh<<<64, 256, 0, stream>>>(h_w1, h_b1, gbuf, Gh);

    // h1: pointfeat part, K=64, bias = Gh[b][o]
    k_mgemm<true, false, true><<<dim3(512, 4), 256, 0, stream>>>(
        h_w1 + 1024, 1088, 64, 512, Y1e, avec + 0, svec + 0, Gh, Y1h,
        sums + 1216, sumsqs + 1216, nullptr, nullptr);
    k_finalize<<<8, 64, 0, stream>>>(sums + 1216, sumsqs + 1216, h_g1, h_be1, avec + 1216, svec + 1216, 512);

    // h2: 512 -> 256
    k_mgemm<true, false, false><<<dim3(512, 2), 256, 0, stream>>>(
        h_w2, 512, 512, 256, Y1h, avec + 1216, svec + 1216, h_b2, Y2h,
        sums + 1728, sumsqs + 1728, nullptr, nullptr);
    k_finalize<<<4, 64, 0, stream>>>(sums + 1728, sumsqs + 1728, h_g2, h_be2, avec + 1728, svec + 1728, 256);

    // h3: 256 -> 128
    k_mgemm<true, false, false><<<dim3(512, 1), 256, 0, stream>>>(
        h_w3, 256, 256, 128, Y2h, avec + 1728, svec + 1728, h_b3, Y3h,
        sums + 1984, sumsqs + 1984, nullptr, nullptr);
    k_finalize<<<2, 64, 0, stream>>>(sums + 1984, sumsqs + 1984, h_g3, h_be3, avec + 1984, svec + 1984, 128);

    // h4 -> weights (+ valid counts), then per-batch WLS solve -> beta
    k_h4<<<256, 256, 0, stream>>>(Y3h, avec + 1984, svec + 1984, h_w4, h_b4, outw, nv);
    k_wls<<<32, 256, 0, stream>>>(pts, outw, nv, beta);
}

// Round 4
// 442.914 us; speedup vs baseline: 4.3779x; 3.3695x over previous
//
#include <hip/hip_runtime.h>
#include <math.h>

// SimpPointNet fused pipeline, round 4: fp16 MFMA GEMMs + atomic-free stats partials
// + coalesced stores via LDS transpose epilogue.
// M = B*N = 65536, m = b*2048 + n. Activations PRE-BN fp16 [M][C]; BN+ReLU applied
// in fp32 during consumer LDS staging. e3 never materialized (per-block max/min
// partials; BN commutes with max). h1 concat-GEMM decomposed. e1 stats analytic.

#define M_TOTAL 65536
#define BN_EPS 1e-5f
#define W_THRESH 1e-4f

typedef __attribute__((ext_vector_type(8))) _Float16 f16x8;
typedef __attribute__((ext_vector_type(4))) float f32x4;

__device__ __forceinline__ unsigned short f2h(float f) {
    _Float16 h = (_Float16)f;  // v_cvt_f16_f32, RNE
    return __builtin_bit_cast(unsigned short, h);
}
__device__ __forceinline__ float h2f(unsigned short u) {
    return (float)__builtin_bit_cast(_Float16, u);
}

// ---- zero stats / counters / moments (ws poisoned 0xAA before every call) ----
__global__ void k_init(float* sums, float* sumsqs, int* nv, float* mom) {
    int i = blockIdx.x * 256 + threadIdx.x;
    if (i < 2112) { sums[i] = 0.f; sumsqs[i] = 0.f; }
    if (i < 32) nv[i] = 0;
    if (i < 12) mom[i] = 0.f;
}

// ---- point second moments over all 65536 pts ----
__global__ void k_moments(const float* __restrict__ pts, float* __restrict__ mom) {
    float s[9] = {0,0,0,0,0,0,0,0,0};
    for (int m = blockIdx.x * 256 + threadIdx.x; m < M_TOTAL; m += gridDim.x * 256) {
        int b = m >> 11, n = m & 2047;
        const float* p = pts + b * 6144 + n;
        float x = p[0], y = p[2048], z = p[4096];
        s[0] += x; s[1] += y; s[2] += z;
        s[3] += x * x; s[4] += y * y; s[5] += z * z;
        s[6] += x * y; s[7] += x * z; s[8] += y * z;
    }
    for (int off = 32; off; off >>= 1)
#pragma unroll
        for (int i = 0; i < 9; i++) s[i] += __shfl_down(s[i], off);
    __shared__ float red[4][9];
    int lane = threadIdx.x & 63, wv = threadIdx.x >> 6;
    if (lane == 0)
        for (int i = 0; i < 9; i++) red[wv][i] = s[i];
    __syncthreads();
    if (threadIdx.x < 9)
        atomicAdd(&mom[threadIdx.x],
                  red[0][threadIdx.x] + red[1][threadIdx.x] + red[2][threadIdx.x] + red[3][threadIdx.x]);
}

// ---- e1 BN params analytically from moments ----
__global__ void k_e1fin(const float* __restrict__ mom, const float* __restrict__ w,
                        const float* __restrict__ bias, const float* __restrict__ g,
                        const float* __restrict__ be, float* __restrict__ a, float* __restrict__ s) {
    int o = threadIdx.x;  // 64
    float w0 = w[o * 3], w1 = w[o * 3 + 1], w2 = w[o * 3 + 2], b = bias[o];
    float wS1 = w0 * mom[0] + w1 * mom[1] + w2 * mom[2];
    float sum = wS1 + 65536.f * b;
    float sumsq = w0 * w0 * mom[3] + w1 * w1 * mom[4] + w2 * w2 * mom[5]
                + 2.f * (w0 * w1 * mom[6] + w0 * w2 * mom[7] + w1 * w2 * mom[8])
                + 2.f * b * wS1 + 65536.f * b * b;
    float mean = sum * (1.f / 65536.f);
    float var = sumsq * (1.f / 65536.f) - mean * mean;
    float ac = g[o] * rsqrtf(var + BN_EPS);
    a[o] = ac;
    s[o] = be[o] - mean * ac;
}

// ---- e1: 3 -> 64, point-major fp16 output [M][64] ----
__global__ void k_e1(const float* __restrict__ pts, const float* __restrict__ w,
                     const float* __restrict__ bias, unsigned short* __restrict__ Y) {
    __shared__ float wl[192], bl[64];
    int tid = threadIdx.x;
    if (tid < 192) wl[tid] = w[tid];
    if (tid < 64) bl[tid] = bias[tid];
    __syncthreads();
    int m = blockIdx.x * 256 + tid;
    int b = m >> 11, n = m & 2047;
    const float* p = pts + b * 6144 + n;
    float px = p[0], py = p[2048], pz = p[4096];
    unsigned short* yr = Y + (size_t)m * 64;
#pragma unroll
    for (int o8 = 0; o8 < 64; o8 += 8) {
        uint4 pk;
        unsigned pkw[4];
#pragma unroll
        for (int t = 0; t < 4; t++) {
            int o = o8 + t * 2;
            float v0 = fmaf(wl[o * 3 + 0], px, fmaf(wl[o * 3 + 1], py, fmaf(wl[o * 3 + 2], pz, bl[o])));
            float v1 = fmaf(wl[o * 3 + 3], px, fmaf(wl[o * 3 + 4], py, fmaf(wl[o * 3 + 5], pz, bl[o + 1])));
            pkw[t] = (unsigned)f2h(v0) | ((unsigned)f2h(v1) << 16);
        }
        pk.x = pkw[0]; pk.y = pkw[1]; pk.z = pkw[2]; pk.w = pkw[3];
        *(uint4*)(yr + o8) = pk;
    }
}

// ---- per-channel BN finalize ----
__global__ void k_finalize(const float* __restrict__ sum, const float* __restrict__ sumsq,
                           const float* __restrict__ g, const float* __restrict__ be,
                           float* __restrict__ a, float* __restrict__ s, int C) {
    int c = blockIdx.x * 64 + threadIdx.x;
    if (c >= C) return;
    float mean = sum[c] * (1.f / M_TOTAL);
    float var = sumsq[c] * (1.f / M_TOTAL) - mean * mean;
    float rstd = rsqrtf(var + BN_EPS);
    float ac = g[c] * rstd;
    a[c] = ac;
    s[c] = be[c] - mean * ac;
}

// ---- reduce slot partials -> sums/sumsqs (8-deep atomics only) ----
// grid (C/64, 8), 256 threads. Ps/Pq layout: [1024 slots][C], slot-major.
__global__ void k_redsum(const float* __restrict__ Ps, const float* __restrict__ Pq,
                         int C, float* __restrict__ sums, float* __restrict__ sumsqs) {
    int cl = threadIdx.x & 63, strip = threadIdx.x >> 6;
    int c = blockIdx.x * 64 + cl;
    int sbase = blockIdx.y * 128;
    float s = 0.f, q = 0.f;
    for (int k = strip; k < 128; k += 4) {
        s += Ps[(size_t)(sbase + k) * C + c];
        q += Pq[(size_t)(sbase + k) * C + c];
    }
    __shared__ float rs[4][64], rq[4][64];
    rs[strip][cl] = s; rq[strip][cl] = q;
    __syncthreads();
    if (threadIdx.x < 64) {
        atomicAdd(&sums[c], rs[0][cl] + rs[1][cl] + rs[2][cl] + rs[3][cl]);
        atomicAdd(&sumsqs[c], rq[0][cl] + rq[1][cl] + rq[2][cl] + rq[3][cl]);
    }
}

// ---- MFMA GEMM: Y[m][o] = bias + sum_k Whf[o][k] * relu(a[k]*X[m][k]+s[k]) ----
// Block tile 128o x 128m, BK=32, 4 waves (2x2), wave = 4x4 tiles of 16x16x32 f16.
// Stats/min-max -> per-slot partials (float4, coalesced; NO atomics).
// STORE path: 4-chunk LDS transpose (reusing sMem) -> fully coalesced uint4 stores.
template <bool STORE, bool MINMAX, bool BIAS_BO>
__launch_bounds__(256, 2)
__global__ void k_mgemm(const float* __restrict__ W, int ldw, int K, int O,
                        const unsigned short* __restrict__ X,
                        const float* __restrict__ a_in, const float* __restrict__ s_in,
                        const float* __restrict__ bias,
                        unsigned short* __restrict__ Y,
                        float* __restrict__ Psum, float* __restrict__ Psq,
                        float* __restrict__ Pmax, float* __restrict__ Pmn) {
    __shared__ __align__(16) short sMem[8192];   // sA[0:4096], sB[4096:8192]; sT aliases [0:4352]
    __shared__ float sa[512], ssh[512];
    short* sA = sMem;
    short* sB = sMem + 4096;
    int tid = threadIdx.x;
    int lane = tid & 63, wave = tid >> 6;
    int wo = wave >> 1, wm = wave & 1;
    int m0 = blockIdx.x * 128, o0 = blockIdx.y * 128;

    for (int c = tid; c < K; c += 256) { sa[c] = a_in[c]; ssh[c] = s_in[c]; }

    f32x4 zero = {0.f, 0.f, 0.f, 0.f};
    f32x4 acc[4][4];
#pragma unroll
    for (int i = 0; i < 4; i++)
#pragma unroll
        for (int j = 0; j < 4; j++) acc[i][j] = zero;

    __syncthreads();

    for (int k0 = 0; k0 < K; k0 += 32) {
        // stage A (weights fp32 -> fp16, frag order)
#pragma unroll
        for (int c = tid; c < 512; c += 256) {
            int oi = c >> 2, kc = c & 3;
            const float* wp = W + (size_t)(o0 + oi) * ldw + k0 + kc * 8;
            float4 wa = *(const float4*)wp;
            float4 wb = *(const float4*)(wp + 4);
            uint4 pk;
            pk.x = (unsigned)f2h(wa.x) | ((unsigned)f2h(wa.y) << 16);
            pk.y = (unsigned)f2h(wa.z) | ((unsigned)f2h(wa.w) << 16);
            pk.z = (unsigned)f2h(wb.x) | ((unsigned)f2h(wb.y) << 16);
            pk.w = (unsigned)f2h(wb.z) | ((unsigned)f2h(wb.w) << 16);
            *(uint4*)&sA[((oi >> 4) * 64 + (oi & 15) + kc * 16) * 8] = pk;
        }
        // stage B (fp16 X -> BN+ReLU in fp32 -> fp16, frag order)
#pragma unroll
        for (int c = tid; c < 512; c += 256) {
            int mi = c >> 2, kc = c & 3;
            const unsigned short* xp = X + (size_t)(m0 + mi) * K + k0 + kc * 8;
            uint4 raw = *(const uint4*)xp;
            unsigned u[4] = {raw.x, raw.y, raw.z, raw.w};
            int kb = k0 + kc * 8;
            unsigned pkw[4];
#pragma unroll
            for (int t = 0; t < 4; t++) {
                float x0 = h2f((unsigned short)(u[t] & 0xffffu));
                float x1 = h2f((unsigned short)(u[t] >> 16));
                float y0 = fmaxf(fmaf(sa[kb + t * 2], x0, ssh[kb + t * 2]), 0.f);
                float y1 = fmaxf(fmaf(sa[kb + t * 2 + 1], x1, ssh[kb + t * 2 + 1]), 0.f);
                pkw[t] = (unsigned)f2h(y0) | ((unsigned)f2h(y1) << 16);
            }
            uint4 pk; pk.x = pkw[0]; pk.y = pkw[1]; pk.z = pkw[2]; pk.w = pkw[3];
            *(uint4*)&sB[((mi >> 4) * 64 + (mi & 15) + kc * 16) * 8] = pk;
        }
        __syncthreads();
        f16x8 af[4], bfr[4];
#pragma unroll
        for (int i = 0; i < 4; i++)
            af[i] = *(const f16x8*)&sA[((wo * 4 + i) * 64 + lane) * 8];
#pragma unroll
        for (int j = 0; j < 4; j++)
            bfr[j] = *(const f16x8*)&sB[((wm * 4 + j) * 64 + lane) * 8];
#pragma unroll
        for (int i = 0; i < 4; i++)
#pragma unroll
            for (int j = 0; j < 4; j++)
                acc[i][j] = __builtin_amdgcn_mfma_f32_16x16x32_f16(af[i], bfr[j], acc[i][j], 0, 0, 0);
        __syncthreads();
    }

    // ---- epilogue. C/D layout: col(=m)=lane&15, row(=o)=quad*4+reg ----
    int q = lane >> 4, lc = lane & 15;
    int bidx = m0 >> 11;
    int slot = blockIdx.x * 2 + wm;   // 1024 unique slots per layer

    // bias add into acc
#pragma unroll
    for (int i = 0; i < 4; i++) {
        int ob = o0 + wo * 64 + i * 16 + q * 4;
        float bv[4];
#pragma unroll
        for (int r = 0; r < 4; r++)
            bv[r] = BIAS_BO ? bias[bidx * O + ob + r] : bias[ob + r];
#pragma unroll
        for (int j = 0; j < 4; j++)
#pragma unroll
            for (int r = 0; r < 4; r++) acc[i][j][r] += bv[r];
    }

    // stats (+minmax) -> coalesced float4 partial writes, no atomics
#pragma unroll
    for (int i = 0; i < 4; i++) {
        int ob = o0 + wo * 64 + i * 16 + q * 4;
        float s4[4] = {0, 0, 0, 0}, q4[4] = {0, 0, 0, 0};
        float mx[4], mn[4];
        if constexpr (MINMAX) {
#pragma unroll
            for (int r = 0; r < 4; r++) { mx[r] = -3.4e38f; mn[r] = 3.4e38f; }
        }
#pragma unroll
        for (int j = 0; j < 4; j++)
#pragma unroll
            for (int r = 0; r < 4; r++) {
                float v = acc[i][j][r];
                s4[r] += v;
                q4[r] += v * v;
                if constexpr (MINMAX) { mx[r] = fmaxf(mx[r], v); mn[r] = fminf(mn[r], v); }
            }
#pragma unroll
        for (int off = 1; off < 16; off <<= 1)
#pragma unroll
            for (int r = 0; r < 4; r++) {
                s4[r] += __shfl_xor(s4[r], off);
                q4[r] += __shfl_xor(q4[r], off);
                if constexpr (MINMAX) {
                    mx[r] = fmaxf(mx[r], __shfl_xor(mx[r], off));
                    mn[r] = fminf(mn[r], __shfl_xor(mn[r], off));
                }
            }
        if (lc == 0) {
            *(float4*)&Psum[(size_t)slot * O + ob] = make_float4(s4[0], s4[1], s4[2], s4[3]);
            *(float4*)&Psq[(size_t)slot * O + ob] = make_float4(q4[0], q4[1], q4[2], q4[3]);
            if constexpr (MINMAX) {
                *(float4*)&Pmax[(size_t)slot * O + ob] = make_float4(mx[0], mx[1], mx[2], mx[3]);
                *(float4*)&Pmn[(size_t)slot * O + ob] = make_float4(mn[0], mn[1], mn[2], mn[3]);
            }
        }
    }

    // coalesced store via LDS transpose: 4 chunks of 32 m-rows (sT aliases sA/sB; dead now)
    if constexpr (STORE) {
        short* sT = sMem;  // 32 rows x 136 halfwords = 4352
#pragma unroll
        for (int ch = 0; ch < 4; ch++) {
            if (wm == (ch >> 1)) {
                int jlo = (ch & 1) * 2;
#pragma unroll
                for (int i = 0; i < 4; i++)
#pragma unroll
                    for (int jj = 0; jj < 2; jj++) {
                        int j = jlo + jj;
                        int row = jj * 16 + lc;
                        int c0 = wo * 64 + i * 16 + q * 4;
                        uint2 pk;
                        pk.x = (unsigned)f2h(acc[i][j][0]) | ((unsigned)f2h(acc[i][j][1]) << 16);
                        pk.y = (unsigned)f2h(acc[i][j][2]) | ((unsigned)f2h(acc[i][j][3]) << 16);
                        *(uint2*)&sT[row * 136 + c0] = pk;
                    }
            }
            __syncthreads();
            {
                int row = tid >> 4, c0 = (tid & 15) * 8;
#pragma unroll
                for (int rr = 0; rr < 2; rr++) {
                    int r2 = row + rr * 16;
                    int m = m0 + ch * 32 + r2;
                    uint4 v = *(const uint4*)&sT[r2 * 136 + c0];
                    *(uint4*)(Y + (size_t)m * O + o0 + c0) = v;
                }
            }
            __syncthreads();
        }
    }
}

// ---- g: reduce e3 min/max partials, apply BN3; write TRANSPOSED gT[o*32+b] ----
__global__ void k_g(const float* __restrict__ Pmax, const float* __restrict__ Pmn,
                    const float* __restrict__ a3, const float* __restrict__ s3,
                    float* __restrict__ gT) {
    int i = blockIdx.x * 256 + threadIdx.x;  // i = b*1024 + o
    if (i >= 32768) return;
    int b = i >> 10, o = i & 1023;
    float mx = -3.4e38f, mn = 3.4e38f;
#pragma unroll 4
    for (int t = 0; t < 32; t++) {
        mx = fmaxf(mx, Pmax[(size_t)(b * 32 + t) * 1024 + o]);
        mn = fminf(mn, Pmn[(size_t)(b * 32 + t) * 1024 + o]);
    }
    float a = a3[o];
    gT[o * 32 + b] = (a >= 0.f) ? fmaf(a, mx, s3[o]) : fmaf(a, mn, s3[o]);
}

// ---- Gh[b][o] = h_b1[o] + sum_{c<1024} h_w1[o*1088+c] * gT[c*32+b] ----
__global__ void k_gh(const float* __restrict__ hw1, const float* __restrict__ hb1,
                     const float* __restrict__ gT, float* __restrict__ Gh) {
    int b = threadIdx.x & 31;
    int o = blockIdx.x * 8 + (threadIdx.x >> 5);
    const float* wr = hw1 + (size_t)o * 1088;
    float acc = hb1[o];
#pragma unroll 4
    for (int c = 0; c < 1024; c++) acc = fmaf(wr[c], gT[c * 32 + b], acc);
    Gh[b * 512 + o] = acc;
}

// ---- h4: 128 -> 1 on [M][128] fp16; weights = 1 + conv + b4; per-batch valid count ----
__global__ void k_h4(const unsigned short* __restrict__ X, const float* __restrict__ a,
                     const float* __restrict__ s, const float* __restrict__ w4,
                     const float* __restrict__ b4, float* __restrict__ outw,
                     int* __restrict__ nv) {
    __shared__ float la[128], ls[128], lw[128];
    int tid = threadIdx.x;
    if (tid < 128) { la[tid] = a[tid]; ls[tid] = s[tid]; lw[tid] = w4[tid]; }
    __syncthreads();
    int m = blockIdx.x * 256 + tid;
    const unsigned short* xr = X + (size_t)m * 128;
    float acc = 0.f;
#pragma unroll
    for (int c = 0; c < 128; c += 8) {
        uint4 raw = *(const uint4*)(xr + c);
        unsigned u[4] = {raw.x, raw.y, raw.z, raw.w};
#pragma unroll
        for (int t = 0; t < 4; t++) {
            float x0 = h2f((unsigned short)(u[t] & 0xffffu));
            float x1 = h2f((unsigned short)(u[t] >> 16));
            float y0 = fmaxf(fmaf(la[c + t * 2], x0, ls[c + t * 2]), 0.f);
            float y1 = fmaxf(fmaf(la[c + t * 2 + 1], x1, ls[c + t * 2 + 1]), 0.f);
            acc = fmaf(lw[c + t * 2], y0, acc);
            acc = fmaf(lw[c + t * 2 + 1], y1, acc);
        }
    }
    float wgt = 1.f + acc + b4[0];
    outw[m] = wgt;
    unsigned long long msk = __ballot(wgt > W_THRESH);
    __shared__ int cnt[4];
    int lane = threadIdx.x & 63, wv = threadIdx.x >> 6;
    if (lane == 0) cnt[wv] = __popcll(msk);
    __syncthreads();
    if (threadIdx.x == 0) atomicAdd(&nv[m >> 11], cnt[0] + cnt[1] + cnt[2] + cnt[3]);
}

// ---- per-batch weighted least squares + 3x3 Cholesky solve ----
__global__ void k_wls(const float* __restrict__ pts, const float* __restrict__ outw,
                      const int* __restrict__ nv, float* __restrict__ beta) {
    int b = blockIdx.x;
    const float* p = pts + b * 6144;
    const float* wr = outw + b * 2048;
    bool use_w = nv[b] > 3;
    float s[9] = {0, 0, 0, 0, 0, 0, 0, 0, 0};
    for (int n = threadIdx.x; n < 2048; n += 256) {
        float wgt = wr[n];
        float we = use_w ? (wgt > W_THRESH ? wgt : 0.f) : 1.f;
        float px = p[n], py = p[2048 + n], pz = p[4096 + n];
        s[0] += we * px * px; s[1] += we * px * py; s[2] += we * px;
        s[3] += we * py * py; s[4] += we * py;      s[5] += we;
        s[6] += we * px * pz; s[7] += we * py * pz; s[8] += we * pz;
    }
    for (int off = 32; off; off >>= 1)
#pragma unroll
        for (int i = 0; i < 9; i++) s[i] += __shfl_down(s[i], off);
    __shared__ float red[4][9];
    int lane = threadIdx.x & 63, wv = threadIdx.x >> 6;
    if (lane == 0)
        for (int i = 0; i < 9; i++) red[wv][i] = s[i];
    __syncthreads();
    if (threadIdx.x == 0) {
        float t[9];
        for (int i = 0; i < 9; i++) t[i] = red[0][i] + red[1][i] + red[2][i] + red[3][i];
        float a11 = t[0], a21 = t[1], a31 = t[2], a22 = t[3], a32 = t[4], a33 = t[5];
        float L11 = sqrtf(a11);
        float L21 = a21 / L11, L31 = a31 / L11;
        float L22 = sqrtf(a22 - L21 * L21);
        float L32 = (a32 - L31 * L21) / L22;
        float L33 = sqrtf(a33 - L31 * L31 - L32 * L32);
        float u1 = t[6] / L11;
        float u2 = (t[7] - L21 * u1) / L22;
        float u3 = (t[8] - L31 * u1 - L32 * u2) / L33;
        float b3 = u3 / L33;
        float b2 = (u2 - L32 * b3) / L22;
        float b1 = (u1 - L21 * b2 - L31 * b3) / L11;
        beta[b * 3 + 0] = b1;
        beta[b * 3 + 1] = b2;
        beta[b * 3 + 2] = b3;
    }
}

extern "C" void kernel_launch(void* const* d_in, const int* in_sizes, int n_in,
                              void* d_out, int out_size, void* d_ws, size_t ws_size,
                              hipStream_t stream) {
    (void)in_sizes; (void)n_in; (void)out_size; (void)ws_size;
    const float* pts   = (const float*)d_in[0];
    const float* e_w1  = (const float*)d_in[1];
    const float* e_b1  = (const float*)d_in[2];
    const float* e_g1  = (const float*)d_in[3];
    const float* e_be1 = (const float*)d_in[4];
    const float* e_w2  = (const float*)d_in[5];
    const float* e_b2  = (const float*)d_in[6];
    const float* e_g2  = (const float*)d_in[7];
    const float* e_be2 = (const float*)d_in[8];
    const float* e_w3  = (const float*)d_in[9];
    const float* e_b3  = (const float*)d_in[10];
    const float* e_g3  = (const float*)d_in[11];
    const float* e_be3 = (const float*)d_in[12];
    const float* h_w1  = (const float*)d_in[13];
    const float* h_b1  = (const float*)d_in[14];
    const float* h_g1  = (const float*)d_in[15];
    const float* h_be1 = (const float*)d_in[16];
    const float* h_w2  = (const float*)d_in[17];
    const float* h_b2  = (const float*)d_in[18];
    const float* h_g2  = (const float*)d_in[19];
    const float* h_be2 = (const float*)d_in[20];
    const float* h_w3  = (const float*)d_in[21];
    const float* h_b3  = (const float*)d_in[22];
    const float* h_g3  = (const float*)d_in[23];
    const float* h_be3 = (const float*)d_in[24];
    const float* h_w4  = (const float*)d_in[25];
    const float* h_b4  = (const float*)d_in[26];

    const size_t M = M_TOTAL;
    unsigned short* wsu = (unsigned short*)d_ws;
    // fp16 activations, point-major [M][C]:
    unsigned short* Y1e = wsu;             // [M][64]
    unsigned short* Y2e = wsu + 64 * M;    // [M][128]
    unsigned short* Y1h = wsu + 192 * M;   // [M][512]
    unsigned short* Y2h = wsu + 704 * M;   // [M][256]
    unsigned short* Y3h = wsu + 960 * M;   // [M][128]
    float* wsf = (float*)(wsu + 1088 * M);
    float* sums   = wsf;                   // 2112 ch: e1@0 e2@64 e3@192 h1@1216 h2@1728 h3@1984
    float* sumsqs = sums + 2112;
    float* avec   = sumsqs + 2112;
    float* svec   = avec + 2112;
    float* mom    = svec + 2112;           // 12 (+4 pad)
    float* Ps   = mom + 16;                // [1024][<=1024] slot partial sums (4 MB)
    float* Pq   = Ps + 1024 * 1024;        // slot partial sumsqs
    float* Pmax = Pq + 1024 * 1024;        // e3 slot max
    float* Pmn  = Pmax + 1024 * 1024;      // e3 slot min
    float* gT   = Pmn + 1024 * 1024;       // [1024][32] transposed g
    float* Gh   = gT + 32768;              // [32][512]
    int* nv     = (int*)(Gh + 16384);      // [32]

    float* beta = (float*)d_out;      // [32][3]
    float* outw = beta + 96;          // [32][2048]

    k_init<<<16, 256, 0, stream>>>(sums, sumsqs, nv, mom);

    // e1: 3 -> 64 (+ analytic BN stats from point moments)
    k_moments<<<64, 256, 0, stream>>>(pts, mom);
    k_e1<<<256, 256, 0, stream>>>(pts, e_w1, e_b1, Y1e);
    k_e1fin<<<1, 64, 0, stream>>>(mom, e_w1, e_b1, e_g1, e_be1, avec + 0, svec + 0);

    // e2: 64 -> 128
    k_mgemm<true, false, false><<<dim3(512, 1), 256, 0, stream>>>(
        e_w2, 64, 64, 128, Y1e, avec + 0, svec + 0, e_b2, Y2e, Ps, Pq, nullptr, nullptr);
    k_redsum<<<dim3(2, 8), 256, 0, stream>>>(Ps, Pq, 128, sums + 64, sumsqs + 64);
    k_finalize<<<2, 64, 0, stream>>>(sums + 64, sumsqs + 64, e_g2, e_be2, avec + 64, svec + 64, 128);

    // e3: 128 -> 1024, no store, stats + per-slot max/min partials
    k_mgemm<false, true, false><<<dim3(512, 8), 256, 0, stream>>>(
        e_w3, 128, 128, 1024, Y2e, avec + 64, svec + 64, e_b3, nullptr, Ps, Pq, Pmax, Pmn);
    k_redsum<<<dim3(16, 8), 256, 0, stream>>>(Ps, Pq, 1024, sums + 192, sumsqs + 192);
    k_finalize<<<16, 64, 0, stream>>>(sums + 192, sumsqs + 192, e_g3, e_be3, avec + 192, svec + 192, 1024);

    // g = BN3(max), then Gh = h_w1[:, :1024] @ g + h_b1
    k_g<<<128, 256, 0, stream>>>(Pmax, Pmn, avec + 192, svec + 192, gT);
    k_gh<<<64, 256, 0, stream>>>(h_w1, h_b1, gT, Gh);

    // h1: pointfeat part, K=64, bias = Gh[b][o]
    k_mgemm<true, false, true><<<dim3(512, 4), 256, 0, stream>>>(
        h_w1 + 1024, 1088, 64, 512, Y1e, avec + 0, svec + 0, Gh, Y1h, Ps, Pq, nullptr, nullptr);
    k_redsum<<<dim3(8, 8), 256, 0, stream>>>(Ps, Pq, 512, sums + 1216, sumsqs + 1216);
    k_finalize<<<8, 64, 0, stream>>>(sums + 1216, sumsqs + 1216, h_g1, h_be1, avec + 1216, svec + 1216, 512);

    // h2: 512 -> 256
    k_mgemm<true, false, false><<<dim3(512, 2), 256, 0, stream>>>(
        h_w2, 512, 512, 256, Y1h, avec + 1216, svec + 1216, h_b2, Y2h, Ps, Pq, nullptr, nullptr);
    k_redsum<<<dim3(4, 8), 256, 0, stream>>>(Ps, Pq, 256, sums + 1728, sumsqs + 1728);
    k_finalize<<<4, 64, 0, stream>>>(sums + 1728, sumsqs + 1728, h_g2, h_be2, avec + 1728, svec + 1728, 256);

    // h3: 256 -> 128
    k_mgemm<true, false, false><<<dim3(512, 1), 256, 0, stream>>>(
        h_w3, 256, 256, 128, Y2h, avec + 1728, svec + 1728, h_b3, Y3h, Ps, Pq, nullptr, nullptr);
    k_redsum<<<dim3(2, 8), 256, 0, stream>>>(Ps, Pq, 128, sums + 1984, sumsqs + 1984);
    k_finalize<<<2, 64, 0, stream>>>(sums + 1984, sumsqs + 1984, h_g3, h_be3, avec + 1984, svec + 1984, 128);

    // h4 -> weights (+ valid counts), then per-batch WLS solve -> beta
    k_h4<<<256, 256, 0, stream>>>(Y3h, avec + 1984, svec + 1984, h_w4, h_b4, outw, nv);
    k_wls<<<32, 256, 0, stream>>>(pts, outw, nv, beta);
}